// Round 8
// baseline (920.863 us; speedup 1.0000x reference)
//
#include <hip/hip_runtime.h>
#include <hip/hip_bf16.h>
#include <math.h>

#define Bn   256
#define Tn   128
#define HID  64
#define MCn  30

typedef __attribute__((ext_vector_type(8))) short bf16x8;
typedef __attribute__((ext_vector_type(4))) float f32x4;

// ---------------------------------------------------------------------------
__device__ __forceinline__ float rcp_(float x) { return __builtin_amdgcn_rcpf(x); }
// tanh(x) = 2/(1+e^{-2x}) - 1 : 5 instrs, NaN-safe at both infinities
__device__ __forceinline__ float tanhf_(float x) {
    float e = __expf(-2.0f * x);
    return __builtin_fmaf(2.0f, rcp_(1.0f + e), -1.0f);
}
__device__ __forceinline__ float sigmoidf_(float x) {
    return rcp_(1.0f + __expf(-x));
}
__device__ __forceinline__ float softplusf_(float z) {
    float e = __expf(-fabsf(z));
    return fmaxf(z, 0.0f) + __logf(1.0f + e);
}
__device__ __forceinline__ unsigned short f2b(float f) {
    union { float f; unsigned u; } v; v.f = f;
    unsigned r = v.u + 0x7FFF + ((v.u >> 16) & 1);
    return (unsigned short)(r >> 16);
}
__device__ __forceinline__ unsigned pk2(float a, float b) {
    union { __hip_bfloat162 h2; unsigned u; } cv;
    cv.h2 = __float22bfloat162_rn(make_float2(a, b));
    return cv.u;
}

// ws images (same as round 6/7):
//  gc[b][256], parv (768 f32), parwb (23552 bf16),
//  seqw1T[(l*64+j)*68+k] = fW1[l][k][j]
//  seqw2T[(l*64+j)*68+k] = fW2[l][k][act+(j&31)+64*(j>>5)]
//  whh260[j*260+k*4+r]   = W_hh[(r*64+j)*64+k]
extern "C" __global__ __launch_bounds__(256)
void prep_kernel(const int* __restrict__ marks, const float* __restrict__ mask,
                 const float* __restrict__ emb, const float* __restrict__ fW0,
                 const float* __restrict__ fW1, const float* __restrict__ fW2,
                 const float* __restrict__ fb0, const float* __restrict__ fb1,
                 const float* __restrict__ fb2, const float* __restrict__ ftw,
                 const float* __restrict__ Wi, const float* __restrict__ W_ih,
                 const float* __restrict__ W_hh,
                 const float* __restrict__ b_ih, const float* __restrict__ b_hh,
                 float* __restrict__ gc, float* __restrict__ invd,
                 float* __restrict__ parv, unsigned short* __restrict__ parwb,
                 float* __restrict__ seqw1T, float* __restrict__ seqw2T,
                 float* __restrict__ whh260)
{
    __shared__ float red[4];
    const int blk = blockIdx.x, tid = threadIdx.x;
    if (blk < Bn) {
        const int mark = marks[blk * Tn + 1];
        const float* er = emb + mark * HID;
        const float* wr = W_ih + tid * 65 + 1;
        float acc = b_ih[tid] + b_hh[tid];
        #pragma unroll
        for (int k = 0; k < HID; k++) acc += er[k] * wr[k];
        gc[blk * 256 + tid] = acc;
    } else if (blk == Bn) {
        float s = 0.f;
        for (int i = tid; i < Bn * Tn; i += 256) s += mask[i];
        #pragma unroll
        for (int off = 32; off >= 1; off >>= 1) s += __shfl_xor(s, off, 64);
        if ((tid & 63) == 0) red[tid >> 6] = s;
        __syncthreads();
        if (tid == 0) invd[0] = 1.0f / (red[0] + red[1] + red[2] + red[3]);
    } else if (blk == Bn + 1) {
        if (tid < 128) {
            int l = tid >> 6, m = tid & 63;
            parv[tid]       = fb0[tid];
            parv[128 + tid] = fW0[(l * 65 + 64) * 64 + m];
            parv[256 + tid] = fb1[tid];
            int act = 32 * (1 - l);
            parv[384 + tid] = fb2[l * 128 + act + (m & 31) + 64 * (m >> 5)];
        }
        if (tid < 64) {
            int l = tid >> 5, i2 = tid & 31, act = 32 * (1 - l);
            parv[512 + tid] = ftw[l * 128 + act + i2];
            parv[576 + tid] = ftw[l * 128 + 64 + act + i2];
            parv[640 + tid] = Wi[tid];
            parv[704 + tid] = 0.f;
        }
    } else if (blk == Bn + 2) {
        for (int i = tid; i < 5120; i += 256) {
            int k = i % 40, m = (i / 40) & 63, l = i / 2560;
            float v = (k < 32) ? fW0[(l * 65 + 32 * l + k) * 64 + m] : 0.f;
            parwb[i] = f2b(v);
        }
    } else if (blk == Bn + 3) {
        for (int i = tid; i < 9216; i += 256) {
            int k = i % 72, m = (i / 72) & 63, l = i / 4608;
            float v = (k < 64) ? fW1[(l * 64 + k) * 64 + m] : 0.f;
            parwb[5120 + i] = f2b(v);
        }
    } else if (blk == Bn + 4) {
        for (int i = tid; i < 9216; i += 256) {
            int k = i % 72, m = (i / 72) & 63, l = i / 4608;
            int act = 32 * (1 - l);
            float v = (k < 64) ? fW2[(l * 64 + k) * 128 + act + (m & 31) + 64 * (m >> 5)] : 0.f;
            parwb[14336 + i] = f2b(v);
        }
    } else if (blk == Bn + 5) {
        for (int i = tid; i < 8704; i += 256) {
            int k = i % 68, j = (i / 68) & 63, l = i / 4352;
            seqw1T[i] = (k < 64) ? fW1[(l * 64 + k) * 64 + j] : 0.f;
        }
    } else if (blk == Bn + 6) {
        for (int i = tid; i < 8704; i += 256) {
            int k = i % 68, j = (i / 68) & 63, l = i / 4352;
            int act = 32 * (1 - l);
            seqw2T[i] = (k < 64) ?
                fW2[(l * 64 + k) * 128 + act + (j & 31) + 64 * (j >> 5)] : 0.f;
        }
    } else {
        for (int i = tid; i < 16640; i += 256) {
            int j = i / 260, rem = i % 260, k = rem >> 2, r = rem & 3;
            whh260[i] = (k < 64) ? W_hh[(r * 64 + j) * 64 + k] : 0.f;
        }
    }
}

// ---------------------------------------------------------------------------
// Sequential kernel: one wave runs TWO independent batch chains (b, b+128)
// interleaved, sharing all weight loads (wave-uniform addresses serve both
// chains' FMAs). Two independent dependency chains give the in-order wave
// ~2x latency hiding that round-7's single chain could not express.
// Zero barriers; 128 blocks x 64 threads.
extern "C" __global__ __launch_bounds__(64, 1)
void seq_kernel(const float* __restrict__ times, const float* __restrict__ mask,
                const float* __restrict__ fW0, const float* __restrict__ fb0,
                const float* __restrict__ fb1, const float* __restrict__ fb2,
                const float* __restrict__ ftw, const float* __restrict__ Wi,
                const float* __restrict__ bi, const float* __restrict__ W_ih,
                const float* __restrict__ gc, const float* __restrict__ seqw1T,
                const float* __restrict__ invd,
                float* __restrict__ h_carry, float* __restrict__ out)
{
    const int j  = threadIdx.x;
    const int bA = blockIdx.x;          // chain A
    const int bB = blockIdx.x + 128;    // chain B

    extern __shared__ float smem[];
    float* w1l  = smem;              // 8704  : w1T, stride 68
    float* w2l  = smem + 8704;       // 8704  : w2T, stride 68
    float* whhl = smem + 17408;      // 16640 : whh260
    float* tlA  = smem + 34048;      // 128
    float* tlB  = smem + 34176;      // 128
    float* mlA  = smem + 34304;      // 128
    float* mlB  = smem + 34432;      // 128
    float* xlA  = smem + 34560;      // 64
    float* xlB  = smem + 34624;      // 64
    float* alA  = smem + 34688;      // 64
    float* alB  = smem + 34752;      // 64
    float* sslA = smem + 34816;      // 64
    float* sslB = smem + 34880;      // 64  (total 34944 floats = 139776 B)

    {
        const float4* s = (const float4*)seqw1T;
        float4* d = (float4*)smem;
        for (int i = j; i < 8512; i += 64) d[i] = s[i];
    }
    tlA[j] = times[bA * Tn + j];   tlA[j + 64] = times[bA * Tn + 64 + j];
    tlB[j] = times[bB * Tn + j];   tlB[j + 64] = times[bB * Tn + 64 + j];
    mlA[j] = mask[bA * Tn + j];    mlA[j + 64] = mask[bA * Tn + 64 + j];
    mlB[j] = mask[bB * Tn + j];    mlB[j + 64] = mask[bB * Tn + 64 + j];

    float w0c[2][32], w0tc[2], b0c[2], b1c[2], b2c[2], ftsc[2], ftsh[2];
    #pragma unroll
    for (int l = 0; l < 2; l++) {
        #pragma unroll
        for (int kk = 0; kk < 32; kk++)
            w0c[l][kk] = fW0[(l * 65 + 32 * l + kk) * 64 + j];
        w0tc[l] = fW0[(l * 65 + 64) * 64 + j];
        b0c[l]  = fb0[l * 64 + j];
        b1c[l]  = fb1[l * 64 + j];
        const int act = 32 * (1 - l);
        b2c[l]  = fb2[l * 128 + act + (j & 31) + 64 * (j >> 5)];
        ftsc[l] = ftw[l * 128 + j];
        ftsh[l] = ftw[l * 128 + 64 + j];
    }
    const float wij = Wi[j];
    const float bi0 = bi[0];
    float wih0[4], gcrA[4], gcrB[4];
    #pragma unroll
    for (int r = 0; r < 4; r++) {
        wih0[r] = W_ih[(r * 64 + j) * 65];
        gcrA[r] = gc[bA * 256 + r * 64 + j];
        gcrB[r] = gc[bB * 256 + r * 64 + j];
    }
    const float idn = invd[0];

    float hA = 0.f, cA = 0.f, nllA = 0.f;
    float hB = 0.f, cB = 0.f, nllB = 0.f;
    for (int t = 0; t < Tn; t++) {
        const float tbA = tlA[t], tbB = tlB[t];
        float tscA[2], tshA[2], tscB[2], tshB[2];
        #pragma unroll
        for (int l = 0; l < 2; l++) {
            tscA[l] = tanhf_(tbA * ftsc[l]);  tshA[l] = tanhf_(tbA * ftsh[l]);
            tscB[l] = tanhf_(tbB * ftsc[l]);  tshB[l] = tanhf_(tbB * ftsh[l]);
        }
        h_carry[(bA * Tn + t) * 64 + j] = hA;    // fire-and-forget
        h_carry[(bB * Tn + t) * 64 + j] = hB;
        float xA = hA, xB = hB;
        xlA[j] = xA;  xlB[j] = xB;
        #pragma unroll
        for (int l = 0; l < 2; l++) {
            const int kb  = 32 * l;
            const int act = 32 * (1 - l);
            // ---- mv1: register weights, dual act streams ----
            {
                float pA0 = b0c[l] + tbA * w0tc[l], pA1 = 0.f, pA2 = 0.f, pA3 = 0.f;
                float pB0 = b0c[l] + tbB * w0tc[l], pB1 = 0.f, pB2 = 0.f, pB3 = 0.f;
                const float4* xA4 = (const float4*)(xlA + kb);
                const float4* xB4 = (const float4*)(xlB + kb);
                #pragma unroll
                for (int k4 = 0; k4 < 8; k4++) {
                    float4 a = xA4[k4], b = xB4[k4];
                    pA0 += a.x * w0c[l][4 * k4 + 0];  pB0 += b.x * w0c[l][4 * k4 + 0];
                    pA1 += a.y * w0c[l][4 * k4 + 1];  pB1 += b.y * w0c[l][4 * k4 + 1];
                    pA2 += a.z * w0c[l][4 * k4 + 2];  pB2 += b.z * w0c[l][4 * k4 + 2];
                    pA3 += a.w * w0c[l][4 * k4 + 3];  pB3 += b.w * w0c[l][4 * k4 + 3];
                }
                alA[j] = tanhf_((pA0 + pA1) + (pA2 + pA3));
                alB[j] = tanhf_((pB0 + pB1) + (pB2 + pB3));
            }
            // ---- mv2: shared weight loads, dual act streams ----
            {
                float pA0 = b1c[l], pA1 = 0.f, pA2 = 0.f, pA3 = 0.f;
                float pB0 = b1c[l], pB1 = 0.f, pB2 = 0.f, pB3 = 0.f;
                const float4* aA4 = (const float4*)alA;
                const float4* aB4 = (const float4*)alB;
                const float*  wp  = w1l + (l * 64 + j) * 68;
                #pragma unroll
                for (int k4 = 0; k4 < 16; k4++) {
                    float4 wv = *(const float4*)(wp + 4 * k4);
                    float4 a = aA4[k4], b = aB4[k4];
                    pA0 += a.x * wv.x;  pB0 += b.x * wv.x;
                    pA1 += a.y * wv.y;  pB1 += b.y * wv.y;
                    pA2 += a.z * wv.z;  pB2 += b.z * wv.z;
                    pA3 += a.w * wv.w;  pB3 += b.w * wv.w;
                }
                alA[j] = tanhf_((pA0 + pA1) + (pA2 + pA3));
                alB[j] = tanhf_((pB0 + pB1) + (pB2 + pB3));
            }
            // ---- mv3: shared weight loads, dual act streams ----
            {
                float pA0 = b2c[l], pA1 = 0.f, pA2 = 0.f, pA3 = 0.f;
                float pB0 = b2c[l], pB1 = 0.f, pB2 = 0.f, pB3 = 0.f;
                const float4* aA4 = (const float4*)alA;
                const float4* aB4 = (const float4*)alB;
                const float*  wp  = w2l + (l * 64 + j) * 68;
                #pragma unroll
                for (int k4 = 0; k4 < 16; k4++) {
                    float4 wv = *(const float4*)(wp + 4 * k4);
                    float4 a = aA4[k4], b = aB4[k4];
                    pA0 += a.x * wv.x;  pB0 += b.x * wv.x;
                    pA1 += a.y * wv.y;  pB1 += b.y * wv.y;
                    pA2 += a.z * wv.z;  pB2 += b.z * wv.z;
                    pA3 += a.w * wv.w;  pB3 += b.w * wv.w;
                }
                sslA[j] = (pA0 + pA1) + (pA2 + pA3);
                sslB[j] = (pB0 + pB1) + (pB2 + pB3);
            }
            // coupling (dual)
            const int idx = (j - act) & 31;
            const bool active = (l == 0) ? (j >= 32) : (j < 32);
            {
                const float scl = sslA[idx], shf = sslA[idx + 32];
                const float xa  = xA * __expf(scl * tscA[l]) + shf * tshA[l];
                xA = active ? xa : xA;
                xlA[j] = xA;
            }
            {
                const float scl = sslB[idx], shf = sslB[idx + 32];
                const float xa  = xB * __expf(scl * tscB[l]) + shf * tshB[l];
                xB = active ? xa : xB;
                xlB[j] = xB;
            }
        }
        out[1 + (bA * Tn + t) * 64 + j] = xA;    // h2, fire-and-forget
        out[1 + (bB * Tn + t) * 64 + j] = xB;
        // nll (dual butterflies, off the recurrence path)
        float vA = xA * wij, vB = xB * wij;
        #pragma unroll
        for (int off = 32; off >= 1; off >>= 1) {
            vA += __shfl_xor(vA, off, 64);
            vB += __shfl_xor(vB, off, 64);
        }
        nllA += -__logf(softplusf_(vA + bi0)) * mlA[t];
        nllB += -__logf(softplusf_(vB + bi0)) * mlB[t];
        // ---- LSTM: shared weight stream, dual gate sets ----
        float gA0 = gcrA[0] + tbA * wih0[0], gB0 = gcrB[0] + tbB * wih0[0];
        float gA1 = gcrA[1] + tbA * wih0[1], gB1 = gcrB[1] + tbB * wih0[1];
        float gA2 = gcrA[2] + tbA * wih0[2], gB2 = gcrB[2] + tbB * wih0[2];
        float gA3 = gcrA[3] + tbA * wih0[3], gB3 = gcrB[3] + tbB * wih0[3];
        {
            const float* wr_base = whhl + j * 260;
            const float4* hA4 = (const float4*)xlA;
            const float4* hB4 = (const float4*)xlB;
            #pragma unroll
            for (int k4 = 0; k4 < 16; k4++) {
                float4 ha = hA4[k4], hb = hB4[k4];
                const float* wr = wr_base + 16 * k4;
                float4 wa = *(const float4*)(wr);
                float4 wb = *(const float4*)(wr + 4);
                float4 wc = *(const float4*)(wr + 8);
                float4 wd = *(const float4*)(wr + 12);
                gA0 += ha.x * wa.x; gA1 += ha.x * wa.y; gA2 += ha.x * wa.z; gA3 += ha.x * wa.w;
                gB0 += hb.x * wa.x; gB1 += hb.x * wa.y; gB2 += hb.x * wa.z; gB3 += hb.x * wa.w;
                gA0 += ha.y * wb.x; gA1 += ha.y * wb.y; gA2 += ha.y * wb.z; gA3 += ha.y * wb.w;
                gB0 += hb.y * wb.x; gB1 += hb.y * wb.y; gB2 += hb.y * wb.z; gB3 += hb.y * wb.w;
                gA0 += ha.z * wc.x; gA1 += ha.z * wc.y; gA2 += ha.z * wc.z; gA3 += ha.z * wc.w;
                gB0 += hb.z * wc.x; gB1 += hb.z * wc.y; gB2 += hb.z * wc.z; gB3 += hb.z * wc.w;
                gA0 += ha.w * wd.x; gA1 += ha.w * wd.y; gA2 += ha.w * wd.z; gA3 += ha.w * wd.w;
                gB0 += hb.w * wd.x; gB1 += hb.w * wd.y; gB2 += hb.w * wd.z; gB3 += hb.w * wd.w;
            }
        }
        cA = sigmoidf_(gA1) * cA + sigmoidf_(gA0) * tanhf_(gA2);
        hA = sigmoidf_(gA3) * tanhf_(cA);
        cB = sigmoidf_(gB1) * cB + sigmoidf_(gB0) * tanhf_(gB2);
        hB = sigmoidf_(gB3) * tanhf_(cB);
    }
    if (j == 0) atomicAdd(out, (nllA + nllB) * idn);
}

// ---------------------------------------------------------------------------
// Parallel kernel, MFMA bf16 (round-6 config: 2 blocks/CU known-good).
extern "C" __global__ __launch_bounds__(256, 2)
void par_kernel(const float* __restrict__ times, const float* __restrict__ mask,
                const float* __restrict__ u, const float* __restrict__ bi,
                const float* __restrict__ invd, const float* __restrict__ parv,
                const unsigned short* __restrict__ parwb,
                const float* __restrict__ h_carry, float* __restrict__ pp)
{
    __shared__ __align__(16) unsigned short sact[128 * 72];
    __shared__ __align__(16) unsigned short sxk1[128 * 40];
    __shared__ __align__(16) unsigned short sx0b[4 * 40];
    __shared__ float pr[4];

    const int tid = threadIdx.x, lane = tid & 63, w = tid >> 6;
    const int quad = lane >> 4, l15 = lane & 15;

    const int q = blockIdx.x * 4 + w;
    const int t = q >> 8, b = q & 255;
    const float tb = times[b * Tn + t];
    const float* hrow = h_carry + (b * Tn + t) * 64;
    if (lane < 32) sx0b[w * 40 + lane] = f2b(hrow[lane]);

    float tsv[2], sclf[2];
    {
        const float base = tb * (1.0f / 30.0f) * invd[0] * mask[b * Tn + t];
        #pragma unroll
        for (int nt = 0; nt < 2; nt++) {
            int mc = nt * 16 + l15;
            bool val = (mc < 30);
            tsv[nt]  = val ? u[t * MCn + mc] * tb : 0.f;
            sclf[nt] = val ? base : 0.f;
        }
    }
    f32x4 xr[2][4];
    #pragma unroll
    for (int mt = 0; mt < 4; mt++) {
        f32x4 v = *(const f32x4*)(hrow + mt * 16 + quad * 4);
        xr[0][mt] = v; xr[1][mt] = v;
    }
    const int srow = w * 32;

    #pragma unroll
    for (int l = 0; l < 2; l++) {
        const unsigned short* wA1 = parwb + l * 2560;
        const unsigned short* wA2 = parwb + 5120 + l * 4608;
        const unsigned short* wA3 = parwb + 14336 + l * 4608;
        // ---- mv1: K=32 ----
        f32x4 c1[4][2];
        if (l == 0) {
            bf16x8 bb = *(const bf16x8*)(sx0b + w * 40 + quad * 8);
            #pragma unroll
            for (int mt = 0; mt < 4; mt++) {
                bf16x8 af = *(const bf16x8*)(wA1 + (mt * 16 + l15) * 40 + quad * 8);
                f32x4 z = {0.f, 0.f, 0.f, 0.f};
                c1[mt][0] = __builtin_amdgcn_mfma_f32_16x16x32_bf16(af, bb, z, 0, 0, 0);
                c1[mt][1] = c1[mt][0];
            }
        } else {
            bf16x8 bf[2];
            #pragma unroll
            for (int nt = 0; nt < 2; nt++)
                bf[nt] = *(const bf16x8*)(sxk1 + (srow + nt * 16 + l15) * 40 + quad * 8);
            #pragma unroll
            for (int mt = 0; mt < 4; mt++) {
                bf16x8 af = *(const bf16x8*)(wA1 + (mt * 16 + l15) * 40 + quad * 8);
                #pragma unroll
                for (int nt = 0; nt < 2; nt++) {
                    f32x4 z = {0.f, 0.f, 0.f, 0.f};
                    c1[mt][nt] = __builtin_amdgcn_mfma_f32_16x16x32_bf16(af, bf[nt], z, 0, 0, 0);
                }
            }
        }
        #pragma unroll
        for (int mt = 0; mt < 4; mt++) {
            f32x4 b0r = *(const f32x4*)(parv + 0   + l * 64 + mt * 16 + quad * 4);
            f32x4 w0r = *(const f32x4*)(parv + 128 + l * 64 + mt * 16 + quad * 4);
            #pragma unroll
            for (int nt = 0; nt < 2; nt++) {
                float v0 = tanhf_(c1[mt][nt][0] + b0r[0] + tsv[nt] * w0r[0]);
                float v1 = tanhf_(c1[mt][nt][1] + b0r[1] + tsv[nt] * w0r[1]);
                float v2 = tanhf_(c1[mt][nt][2] + b0r[2] + tsv[nt] * w0r[2]);
                float v3 = tanhf_(c1[mt][nt][3] + b0r[3] + tsv[nt] * w0r[3]);
                uint2 pk; pk.x = pk2(v0, v1); pk.y = pk2(v2, v3);
                *(uint2*)(sact + (srow + nt * 16 + l15) * 72 + mt * 16 + quad * 4) = pk;
            }
        }
        // ---- mv2: K=64 ----
        f32x4 cc[4][2];
        #pragma unroll
        for (int mt = 0; mt < 4; mt++)
            #pragma unroll
            for (int nt = 0; nt < 2; nt++) cc[mt][nt] = (f32x4){0.f, 0.f, 0.f, 0.f};
        #pragma unroll
        for (int kt = 0; kt < 2; kt++) {
            bf16x8 bf[2];
            #pragma unroll
            for (int nt = 0; nt < 2; nt++)
                bf[nt] = *(const bf16x8*)(sact + (srow + nt * 16 + l15) * 72 + kt * 32 + quad * 8);
            #pragma unroll
            for (int mt = 0; mt < 4; mt++) {
                bf16x8 af = *(const bf16x8*)(wA2 + (mt * 16 + l15) * 72 + kt * 32 + quad * 8);
                #pragma unroll
                for (int nt = 0; nt < 2; nt++)
                    cc[mt][nt] = __builtin_amdgcn_mfma_f32_16x16x32_bf16(af, bf[nt], cc[mt][nt], 0, 0, 0);
            }
        }
        #pragma unroll
        for (int mt = 0; mt < 4; mt++) {
            f32x4 b1r = *(const f32x4*)(parv + 256 + l * 64 + mt * 16 + quad * 4);
            #pragma unroll
            for (int nt = 0; nt < 2; nt++) {
                float v0 = tanhf_(cc[mt][nt][0] + b1r[0]);
                float v1 = tanhf_(cc[mt][nt][1] + b1r[1]);
                float v2 = tanhf_(cc[mt][nt][2] + b1r[2]);
                float v3 = tanhf_(cc[mt][nt][3] + b1r[3]);
                uint2 pk; pk.x = pk2(v0, v1); pk.y = pk2(v2, v3);
                *(uint2*)(sact + (srow + nt * 16 + l15) * 72 + mt * 16 + quad * 4) = pk;
            }
        }
        // ---- mv3: K=64 ----
        f32x4 ssf[4][2];
        #pragma unroll
        for (int mt = 0; mt < 4; mt++)
            #pragma unroll
            for (int nt = 0; nt < 2; nt++) ssf[mt][nt] = (f32x4){0.f, 0.f, 0.f, 0.f};
        #pragma unroll
        for (int kt = 0; kt < 2; kt++) {
            bf16x8 bf[2];
            #pragma unroll
            for (int nt = 0; nt < 2; nt++)
                bf[nt] = *(const bf16x8*)(sact + (srow + nt * 16 + l15) * 72 + kt * 32 + quad * 8);
            #pragma unroll
            for (int mt = 0; mt < 4; mt++) {
                bf16x8 af = *(const bf16x8*)(wA3 + (mt * 16 + l15) * 72 + kt * 32 + quad * 8);
                #pragma unroll
                for (int nt = 0; nt < 2; nt++)
                    ssf[mt][nt] = __builtin_amdgcn_mfma_f32_16x16x32_bf16(af, bf[nt], ssf[mt][nt], 0, 0, 0);
            }
        }
        // coupling in registers
        #pragma unroll
        for (int mt2 = 0; mt2 < 2; mt2++) {
            f32x4 b2s = *(const f32x4*)(parv + 384 + l * 64 +      mt2 * 16 + quad * 4);
            f32x4 b2h = *(const f32x4*)(parv + 384 + l * 64 + 32 + mt2 * 16 + quad * 4);
            f32x4 fa  = *(const f32x4*)(parv + 512 + l * 32 + mt2 * 16 + quad * 4);
            f32x4 fb  = *(const f32x4*)(parv + 576 + l * 32 + mt2 * 16 + quad * 4);
            const int xm = (l == 0) ? (mt2 + 2) : mt2;
            #pragma unroll
            for (int nt = 0; nt < 2; nt++) {
                #pragma unroll
                for (int r = 0; r < 4; r++) {
                    float sc  = ssf[mt2][nt][r] + b2s[r];
                    float sh  = ssf[mt2 + 2][nt][r] + b2h[r];
                    float tsc = tanhf_(tsv[nt] * fa[r]);
                    float tsh = tanhf_(tsv[nt] * fb[r]);
                    float xv  = xr[nt][xm][r];
                    xr[nt][xm][r] = xv * __expf(sc * tsc) + sh * tsh;
                }
                if (l == 0) {
                    uint2 pk;
                    pk.x = pk2(xr[nt][xm][0], xr[nt][xm][1]);
                    pk.y = pk2(xr[nt][xm][2], xr[nt][xm][3]);
                    *(uint2*)(sxk1 + (srow + nt * 16 + l15) * 40 + mt2 * 16 + quad * 4) = pk;
                }
            }
        }
    }
    // ---- intensity + per-block loss partial ----
    float contrib = 0.f;
    const float bi0 = bi[0];
    #pragma unroll
    for (int nt = 0; nt < 2; nt++) {
        float d0 = 0.f, d1 = 0.f;
        #pragma unroll
        for (int mt = 0; mt < 4; mt++) {
            f32x4 wi4 = *(const f32x4*)(parv + 640 + mt * 16 + quad * 4);
            d0 += xr[nt][mt][0] * wi4[0] + xr[nt][mt][2] * wi4[2];
            d1 += xr[nt][mt][1] * wi4[1] + xr[nt][mt][3] * wi4[3];
        }
        float d = d0 + d1;
        d += __shfl_xor(d, 16, 64);
        d += __shfl_xor(d, 32, 64);
        contrib += softplusf_(d + bi0) * sclf[nt];
    }
    if (quad != 0) contrib = 0.f;
    #pragma unroll
    for (int off = 1; off <= 8; off <<= 1) contrib += __shfl_xor(contrib, off, 64);
    if (l15 == 0 && quad == 0) pr[w] = contrib;
    __syncthreads();
    if (tid == 0) pp[blockIdx.x] = pr[0] + pr[1] + pr[2] + pr[3];
}

// ---------------------------------------------------------------------------
extern "C" __global__ __launch_bounds__(256)
void fin_kernel(const float* __restrict__ pp, float* __restrict__ out)
{
    __shared__ float r4[4];
    const int tid = threadIdx.x;
    float s = 0.f;
    for (int i = tid; i < (Bn * Tn) / 4; i += 256) s += pp[i];
    #pragma unroll
    for (int off = 32; off >= 1; off >>= 1) s += __shfl_xor(s, off, 64);
    if ((tid & 63) == 0) r4[tid >> 6] = s;
    __syncthreads();
    if (tid == 0) atomicAdd(out, r4[0] + r4[1] + r4[2] + r4[3]);
}

// ---------------------------------------------------------------------------
extern "C" void kernel_launch(void* const* d_in, const int* in_sizes, int n_in,
                              void* d_out, int out_size, void* d_ws, size_t ws_size,
                              hipStream_t stream)
{
    const float* times = (const float*)d_in[0];
    const int*   marks = (const int*)  d_in[1];
    const float* mask  = (const float*)d_in[2];
    const float* u     = (const float*)d_in[3];
    const float* emb   = (const float*)d_in[4];
    const float* fW0   = (const float*)d_in[5];
    const float* fb0   = (const float*)d_in[6];
    const float* fW1   = (const float*)d_in[7];
    const float* fb1   = (const float*)d_in[8];
    const float* fW2   = (const float*)d_in[9];
    const float* fb2   = (const float*)d_in[10];
    const float* ftw   = (const float*)d_in[11];
    const float* Wi    = (const float*)d_in[12];
    const float* bi    = (const float*)d_in[13];
    const float* W_ih  = (const float*)d_in[14];
    const float* W_hh  = (const float*)d_in[15];
    const float* b_ih  = (const float*)d_in[16];
    const float* b_hh  = (const float*)d_in[17];
    float* out = (float*)d_out;

    float* wsp     = (float*)d_ws;
    float* h_carry = wsp;                   // 2,097,152
    float* gc      = h_carry + 2097152;     // 65,536
    float* invd    = gc + 65536;            // 4
    float* seqw1T  = invd + 4;              // 8,704  (w1l/w2l/whhl contiguous)
    float* seqw2T  = seqw1T + 8704;         // 8,704
    float* whh260  = seqw2T + 8704;         // 16,640
    float* parv    = whh260 + 16640;        // 768
    unsigned short* parwb = (unsigned short*)(parv + 768);   // 23,552 ushorts
    float* pp      = (float*)(parwb + 23552);                // 8,192

    hipMemsetAsync(d_out, 0, sizeof(float), stream);

    const int SEQ_SMEM = 34944 * 4;   // 139,776 B
    hipFuncSetAttribute((const void*)seq_kernel,
                        hipFuncAttributeMaxDynamicSharedMemorySize, SEQ_SMEM);

    prep_kernel<<<Bn + 8, 256, 0, stream>>>(marks, mask, emb, fW0, fW1, fW2,
                                            fb0, fb1, fb2, ftw, Wi, W_ih, W_hh,
                                            b_ih, b_hh, gc, invd, parv, parwb,
                                            seqw1T, seqw2T, whh260);
    seq_kernel<<<Bn / 2, 64, SEQ_SMEM, stream>>>(times, mask, fW0, fb0, fb1, fb2,
                                                 ftw, Wi, bi, W_ih, gc, seqw1T,
                                                 invd, h_carry, out);
    par_kernel<<<(Bn * Tn) / 4, 256, 0, stream>>>(
        times, mask, u, bi, invd, parv, parwb, h_carry, pp);
    fin_kernel<<<1, 256, 0, stream>>>(pp, out);
}

// Round 9
// 876.982 us; speedup vs baseline: 1.0500x; 1.0500x over previous
//
#include <hip/hip_runtime.h>
#include <hip/hip_bf16.h>
#include <math.h>

#define Bn   256
#define Tn   128
#define HID  64
#define MCn  30

typedef __attribute__((ext_vector_type(8))) short bf16x8;
typedef __attribute__((ext_vector_type(4))) float f32x4;

// ---------------------------------------------------------------------------
__device__ __forceinline__ float rcp_(float x) { return __builtin_amdgcn_rcpf(x); }
// tanh(x) = 2/(1+e^{-2x}) - 1 : 5 instrs, NaN-safe at both infinities
__device__ __forceinline__ float tanhf_(float x) {
    float e = __expf(-2.0f * x);
    return __builtin_fmaf(2.0f, rcp_(1.0f + e), -1.0f);
}
__device__ __forceinline__ float sigmoidf_(float x) {
    return rcp_(1.0f + __expf(-x));
}
__device__ __forceinline__ float softplusf_(float z) {
    float e = __expf(-fabsf(z));
    return fmaxf(z, 0.0f) + __logf(1.0f + e);
}
__device__ __forceinline__ unsigned short f2b(float f) {
    union { float f; unsigned u; } v; v.f = f;
    unsigned r = v.u + 0x7FFF + ((v.u >> 16) & 1);
    return (unsigned short)(r >> 16);
}
__device__ __forceinline__ unsigned pk2(float a, float b) {
    union { __hip_bfloat162 h2; unsigned u; } cv;
    cv.h2 = __float22bfloat162_rn(make_float2(a, b));
    return cv.u;
}

// ws images (same as rounds 6-8):
//  gc[b][256], parv (768 f32), parwb (23552 bf16),
//  seqw1T[(l*64+j)*68+k] = fW1[l][k][j]
//  seqw2T[(l*64+j)*68+k] = fW2[l][k][act+(j&31)+64*(j>>5)]
//  whh260[j*260+k*4+r]   = W_hh[(r*64+j)*64+k]
extern "C" __global__ __launch_bounds__(256)
void prep_kernel(const int* __restrict__ marks, const float* __restrict__ mask,
                 const float* __restrict__ emb, const float* __restrict__ fW0,
                 const float* __restrict__ fW1, const float* __restrict__ fW2,
                 const float* __restrict__ fb0, const float* __restrict__ fb1,
                 const float* __restrict__ fb2, const float* __restrict__ ftw,
                 const float* __restrict__ Wi, const float* __restrict__ W_ih,
                 const float* __restrict__ W_hh,
                 const float* __restrict__ b_ih, const float* __restrict__ b_hh,
                 float* __restrict__ gc, float* __restrict__ invd,
                 float* __restrict__ parv, unsigned short* __restrict__ parwb,
                 float* __restrict__ seqw1T, float* __restrict__ seqw2T,
                 float* __restrict__ whh260)
{
    __shared__ float red[4];
    const int blk = blockIdx.x, tid = threadIdx.x;
    if (blk < Bn) {
        const int mark = marks[blk * Tn + 1];
        const float* er = emb + mark * HID;
        const float* wr = W_ih + tid * 65 + 1;
        float acc = b_ih[tid] + b_hh[tid];
        #pragma unroll
        for (int k = 0; k < HID; k++) acc += er[k] * wr[k];
        gc[blk * 256 + tid] = acc;
    } else if (blk == Bn) {
        float s = 0.f;
        for (int i = tid; i < Bn * Tn; i += 256) s += mask[i];
        #pragma unroll
        for (int off = 32; off >= 1; off >>= 1) s += __shfl_xor(s, off, 64);
        if ((tid & 63) == 0) red[tid >> 6] = s;
        __syncthreads();
        if (tid == 0) invd[0] = 1.0f / (red[0] + red[1] + red[2] + red[3]);
    } else if (blk == Bn + 1) {
        if (tid < 128) {
            int l = tid >> 6, m = tid & 63;
            parv[tid]       = fb0[tid];
            parv[128 + tid] = fW0[(l * 65 + 64) * 64 + m];
            parv[256 + tid] = fb1[tid];
            int act = 32 * (1 - l);
            parv[384 + tid] = fb2[l * 128 + act + (m & 31) + 64 * (m >> 5)];
        }
        if (tid < 64) {
            int l = tid >> 5, i2 = tid & 31, act = 32 * (1 - l);
            parv[512 + tid] = ftw[l * 128 + act + i2];
            parv[576 + tid] = ftw[l * 128 + 64 + act + i2];
            parv[640 + tid] = Wi[tid];
            parv[704 + tid] = 0.f;
        }
    } else if (blk == Bn + 2) {
        for (int i = tid; i < 5120; i += 256) {
            int k = i % 40, m = (i / 40) & 63, l = i / 2560;
            float v = (k < 32) ? fW0[(l * 65 + 32 * l + k) * 64 + m] : 0.f;
            parwb[i] = f2b(v);
        }
    } else if (blk == Bn + 3) {
        for (int i = tid; i < 9216; i += 256) {
            int k = i % 72, m = (i / 72) & 63, l = i / 4608;
            float v = (k < 64) ? fW1[(l * 64 + k) * 64 + m] : 0.f;
            parwb[5120 + i] = f2b(v);
        }
    } else if (blk == Bn + 4) {
        for (int i = tid; i < 9216; i += 256) {
            int k = i % 72, m = (i / 72) & 63, l = i / 4608;
            int act = 32 * (1 - l);
            float v = (k < 64) ? fW2[(l * 64 + k) * 128 + act + (m & 31) + 64 * (m >> 5)] : 0.f;
            parwb[14336 + i] = f2b(v);
        }
    } else if (blk == Bn + 5) {
        for (int i = tid; i < 8704; i += 256) {
            int k = i % 68, j = (i / 68) & 63, l = i / 4352;
            seqw1T[i] = (k < 64) ? fW1[(l * 64 + k) * 64 + j] : 0.f;
        }
    } else if (blk == Bn + 6) {
        for (int i = tid; i < 8704; i += 256) {
            int k = i % 68, j = (i / 68) & 63, l = i / 4352;
            int act = 32 * (1 - l);
            seqw2T[i] = (k < 64) ?
                fW2[(l * 64 + k) * 128 + act + (j & 31) + 64 * (j >> 5)] : 0.f;
        }
    } else {
        for (int i = tid; i < 16640; i += 256) {
            int j = i / 260, rem = i % 260, k = rem >> 2, r = rem & 3;
            whh260[i] = (k < 64) ? W_hh[(r * 64 + j) * 64 + k] : 0.f;
        }
    }
}

// ---------------------------------------------------------------------------
// Sequential kernel: one wave per batch element (256 blocks), zero barriers.
// COUNTER SPLIT: activation round-trips stay in LDS (lgkmcnt: short, precise
// waits); the t-invariant mv2/mv3 weight streams load from GLOBAL (L1/L2-
// resident, vmcnt: independent of the DS chain, prefetches deep). LSTM
// weights (65 KB > L1) stay in LDS. This decouples the weight stream from
// the dependent-activation waits that serialized rounds 6/7 at ~8000 cyc/step.
extern "C" __global__ __launch_bounds__(64, 1)
void seq_kernel(const float* __restrict__ times, const float* __restrict__ mask,
                const float* __restrict__ fW0, const float* __restrict__ fb0,
                const float* __restrict__ fb1, const float* __restrict__ fb2,
                const float* __restrict__ ftw, const float* __restrict__ Wi,
                const float* __restrict__ bi, const float* __restrict__ W_ih,
                const float* __restrict__ gc, const float* __restrict__ seqw1T,
                const float* __restrict__ seqw2T, const float* __restrict__ whh260,
                const float* __restrict__ invd,
                float* __restrict__ h_carry, float* __restrict__ out)
{
    const int j = threadIdx.x;
    const int b = blockIdx.x;

    __shared__ __align__(16) float whhl[16640];   // LSTM weights, stride 260
    __shared__ __align__(16) float tl[128];
    __shared__ __align__(16) float ml[128];
    __shared__ __align__(16) float xl[64];
    __shared__ __align__(16) float al[64];
    __shared__ __align__(16) float ssl[64];

    // stage LSTM weights (one-time, 4160 float4)
    {
        const float4* s = (const float4*)whh260;
        float4* d = (float4*)whhl;
        for (int i = j; i < 4160; i += 64) d[i] = s[i];
    }
    tl[j] = times[b * Tn + j];       tl[j + 64] = times[b * Tn + 64 + j];
    ml[j] = mask[b * Tn + j];        ml[j + 64] = mask[b * Tn + 64 + j];

    float w0c[2][32], w0tc[2], b0c[2], b1c[2], b2c[2], ftsc[2], ftsh[2];
    #pragma unroll
    for (int l = 0; l < 2; l++) {
        #pragma unroll
        for (int kk = 0; kk < 32; kk++)
            w0c[l][kk] = fW0[(l * 65 + 32 * l + kk) * 64 + j];
        w0tc[l] = fW0[(l * 65 + 64) * 64 + j];
        b0c[l]  = fb0[l * 64 + j];
        b1c[l]  = fb1[l * 64 + j];
        const int act = 32 * (1 - l);
        b2c[l]  = fb2[l * 128 + act + (j & 31) + 64 * (j >> 5)];
        ftsc[l] = ftw[l * 128 + j];
        ftsh[l] = ftw[l * 128 + 64 + j];
    }
    const float wij = Wi[j];
    const float bi0 = bi[0];
    float wih0[4], gcr[4];
    #pragma unroll
    for (int r = 0; r < 4; r++) {
        wih0[r] = W_ih[(r * 64 + j) * 65];
        gcr[r]  = gc[b * 256 + r * 64 + j];
    }
    const float idn = invd[0];
    // per-lane global weight column pointers (t-invariant)
    const float4* w1g[2], * w2g[2];
    #pragma unroll
    for (int l = 0; l < 2; l++) {
        w1g[l] = (const float4*)(seqw1T + (l * 64 + j) * 68);
        w2g[l] = (const float4*)(seqw2T + (l * 64 + j) * 68);
    }

    float h = 0.f, c = 0.f, nllacc = 0.f;
    for (int t = 0; t < Tn; t++) {
        const float tb = tl[t];
        float tscv[2], tshv[2];
        #pragma unroll
        for (int l = 0; l < 2; l++) {
            tscv[l] = tanhf_(tb * ftsc[l]);
            tshv[l] = tanhf_(tb * ftsh[l]);
        }
        h_carry[(b * Tn + t) * 64 + j] = h;      // fire-and-forget
        float x = h;
        xl[j] = x;
        #pragma unroll
        for (int l = 0; l < 2; l++) {
            const int kb  = 32 * l;
            const int act = 32 * (1 - l);
            // ---- mv1: LDS acts x register weights ----
            {
                float p0 = b0c[l] + tb * w0tc[l], p1 = 0.f, p2 = 0.f, p3 = 0.f;
                const float4* xv4 = (const float4*)(xl + kb);
                #pragma unroll
                for (int k4 = 0; k4 < 8; k4++) {
                    float4 xv = xv4[k4];
                    p0 += xv.x * w0c[l][4 * k4 + 0];
                    p1 += xv.y * w0c[l][4 * k4 + 1];
                    p2 += xv.z * w0c[l][4 * k4 + 2];
                    p3 += xv.w * w0c[l][4 * k4 + 3];
                }
                al[j] = tanhf_((p0 + p1) + (p2 + p3));
            }
            // ---- mv2: LDS acts x GLOBAL weight stream (vmcnt) ----
            {
                float p0 = b1c[l], p1 = 0.f, p2 = 0.f, p3 = 0.f;
                const float4* av4 = (const float4*)al;
                const float4* wp  = w1g[l];
                #pragma unroll
                for (int k4 = 0; k4 < 16; k4++) {
                    float4 wv = wp[k4];
                    float4 av = av4[k4];
                    p0 += av.x * wv.x;
                    p1 += av.y * wv.y;
                    p2 += av.z * wv.z;
                    p3 += av.w * wv.w;
                }
                al[j] = tanhf_((p0 + p1) + (p2 + p3));
            }
            // ---- mv3: LDS acts x GLOBAL weight stream (vmcnt) ----
            {
                float p0 = b2c[l], p1 = 0.f, p2 = 0.f, p3 = 0.f;
                const float4* av4 = (const float4*)al;
                const float4* wp  = w2g[l];
                #pragma unroll
                for (int k4 = 0; k4 < 16; k4++) {
                    float4 wv = wp[k4];
                    float4 av = av4[k4];
                    p0 += av.x * wv.x;
                    p1 += av.y * wv.y;
                    p2 += av.z * wv.z;
                    p3 += av.w * wv.w;
                }
                ssl[j] = (p0 + p1) + (p2 + p3);
            }
            // coupling
            const int idx = (j - act) & 31;
            const float scl = ssl[idx];
            const float shf = ssl[idx + 32];
            const float xa  = x * __expf(scl * tscv[l]) + shf * tshv[l];
            const bool active = (l == 0) ? (j >= 32) : (j < 32);
            x = active ? xa : x;
            xl[j] = x;
        }
        out[1 + (b * Tn + t) * 64 + j] = x;      // h2, fire-and-forget
        // nll (off the recurrence path)
        float v = x * wij;
        #pragma unroll
        for (int off = 32; off >= 1; off >>= 1) v += __shfl_xor(v, off, 64);
        nllacc += -__logf(softplusf_(v + bi0)) * ml[t];
        // ---- LSTM: LDS weight stream + LDS acts ----
        float g0 = gcr[0] + tb * wih0[0];
        float g1 = gcr[1] + tb * wih0[1];
        float g2 = gcr[2] + tb * wih0[2];
        float g3 = gcr[3] + tb * wih0[3];
        {
            const float*  wr_base = whhl + j * 260;
            const float4* hv4 = (const float4*)xl;
            #pragma unroll
            for (int k4 = 0; k4 < 16; k4++) {
                float4 hv = hv4[k4];
                const float* wr = wr_base + 16 * k4;
                float4 wa = *(const float4*)(wr);
                float4 wb = *(const float4*)(wr + 4);
                float4 wc = *(const float4*)(wr + 8);
                float4 wd = *(const float4*)(wr + 12);
                g0 += hv.x * wa.x; g1 += hv.x * wa.y; g2 += hv.x * wa.z; g3 += hv.x * wa.w;
                g0 += hv.y * wb.x; g1 += hv.y * wb.y; g2 += hv.y * wb.z; g3 += hv.y * wb.w;
                g0 += hv.z * wc.x; g1 += hv.z * wc.y; g2 += hv.z * wc.z; g3 += hv.z * wc.w;
                g0 += hv.w * wd.x; g1 += hv.w * wd.y; g2 += hv.w * wd.z; g3 += hv.w * wd.w;
            }
        }
        c = sigmoidf_(g1) * c + sigmoidf_(g0) * tanhf_(g2);
        h = sigmoidf_(g3) * tanhf_(c);
    }
    if (j == 0) atomicAdd(out, nllacc * idn);
}

// ---------------------------------------------------------------------------
// Parallel kernel, MFMA bf16 (round-6 config: 2 blocks/CU known-good).
extern "C" __global__ __launch_bounds__(256, 2)
void par_kernel(const float* __restrict__ times, const float* __restrict__ mask,
                const float* __restrict__ u, const float* __restrict__ bi,
                const float* __restrict__ invd, const float* __restrict__ parv,
                const unsigned short* __restrict__ parwb,
                const float* __restrict__ h_carry, float* __restrict__ pp)
{
    __shared__ __align__(16) unsigned short sact[128 * 72];
    __shared__ __align__(16) unsigned short sxk1[128 * 40];
    __shared__ __align__(16) unsigned short sx0b[4 * 40];
    __shared__ float pr[4];

    const int tid = threadIdx.x, lane = tid & 63, w = tid >> 6;
    const int quad = lane >> 4, l15 = lane & 15;

    const int q = blockIdx.x * 4 + w;
    const int t = q >> 8, b = q & 255;
    const float tb = times[b * Tn + t];
    const float* hrow = h_carry + (b * Tn + t) * 64;
    if (lane < 32) sx0b[w * 40 + lane] = f2b(hrow[lane]);

    float tsv[2], sclf[2];
    {
        const float base = tb * (1.0f / 30.0f) * invd[0] * mask[b * Tn + t];
        #pragma unroll
        for (int nt = 0; nt < 2; nt++) {
            int mc = nt * 16 + l15;
            bool val = (mc < 30);
            tsv[nt]  = val ? u[t * MCn + mc] * tb : 0.f;
            sclf[nt] = val ? base : 0.f;
        }
    }
    f32x4 xr[2][4];
    #pragma unroll
    for (int mt = 0; mt < 4; mt++) {
        f32x4 v = *(const f32x4*)(hrow + mt * 16 + quad * 4);
        xr[0][mt] = v; xr[1][mt] = v;
    }
    const int srow = w * 32;

    #pragma unroll
    for (int l = 0; l < 2; l++) {
        const unsigned short* wA1 = parwb + l * 2560;
        const unsigned short* wA2 = parwb + 5120 + l * 4608;
        const unsigned short* wA3 = parwb + 14336 + l * 4608;
        // ---- mv1: K=32 ----
        f32x4 c1[4][2];
        if (l == 0) {
            bf16x8 bb = *(const bf16x8*)(sx0b + w * 40 + quad * 8);
            #pragma unroll
            for (int mt = 0; mt < 4; mt++) {
                bf16x8 af = *(const bf16x8*)(wA1 + (mt * 16 + l15) * 40 + quad * 8);
                f32x4 z = {0.f, 0.f, 0.f, 0.f};
                c1[mt][0] = __builtin_amdgcn_mfma_f32_16x16x32_bf16(af, bb, z, 0, 0, 0);
                c1[mt][1] = c1[mt][0];
            }
        } else {
            bf16x8 bf[2];
            #pragma unroll
            for (int nt = 0; nt < 2; nt++)
                bf[nt] = *(const bf16x8*)(sxk1 + (srow + nt * 16 + l15) * 40 + quad * 8);
            #pragma unroll
            for (int mt = 0; mt < 4; mt++) {
                bf16x8 af = *(const bf16x8*)(wA1 + (mt * 16 + l15) * 40 + quad * 8);
                #pragma unroll
                for (int nt = 0; nt < 2; nt++) {
                    f32x4 z = {0.f, 0.f, 0.f, 0.f};
                    c1[mt][nt] = __builtin_amdgcn_mfma_f32_16x16x32_bf16(af, bf[nt], z, 0, 0, 0);
                }
            }
        }
        #pragma unroll
        for (int mt = 0; mt < 4; mt++) {
            f32x4 b0r = *(const f32x4*)(parv + 0   + l * 64 + mt * 16 + quad * 4);
            f32x4 w0r = *(const f32x4*)(parv + 128 + l * 64 + mt * 16 + quad * 4);
            #pragma unroll
            for (int nt = 0; nt < 2; nt++) {
                float v0 = tanhf_(c1[mt][nt][0] + b0r[0] + tsv[nt] * w0r[0]);
                float v1 = tanhf_(c1[mt][nt][1] + b0r[1] + tsv[nt] * w0r[1]);
                float v2 = tanhf_(c1[mt][nt][2] + b0r[2] + tsv[nt] * w0r[2]);
                float v3 = tanhf_(c1[mt][nt][3] + b0r[3] + tsv[nt] * w0r[3]);
                uint2 pk; pk.x = pk2(v0, v1); pk.y = pk2(v2, v3);
                *(uint2*)(sact + (srow + nt * 16 + l15) * 72 + mt * 16 + quad * 4) = pk;
            }
        }
        // ---- mv2: K=64 ----
        f32x4 cc[4][2];
        #pragma unroll
        for (int mt = 0; mt < 4; mt++)
            #pragma unroll
            for (int nt = 0; nt < 2; nt++) cc[mt][nt] = (f32x4){0.f, 0.f, 0.f, 0.f};
        #pragma unroll
        for (int kt = 0; kt < 2; kt++) {
            bf16x8 bf[2];
            #pragma unroll
            for (int nt = 0; nt < 2; nt++)
                bf[nt] = *(const bf16x8*)(sact + (srow + nt * 16 + l15) * 72 + kt * 32 + quad * 8);
            #pragma unroll
            for (int mt = 0; mt < 4; mt++) {
                bf16x8 af = *(const bf16x8*)(wA2 + (mt * 16 + l15) * 72 + kt * 32 + quad * 8);
                #pragma unroll
                for (int nt = 0; nt < 2; nt++)
                    cc[mt][nt] = __builtin_amdgcn_mfma_f32_16x16x32_bf16(af, bf[nt], cc[mt][nt], 0, 0, 0);
            }
        }
        #pragma unroll
        for (int mt = 0; mt < 4; mt++) {
            f32x4 b1r = *(const f32x4*)(parv + 256 + l * 64 + mt * 16 + quad * 4);
            #pragma unroll
            for (int nt = 0; nt < 2; nt++) {
                float v0 = tanhf_(cc[mt][nt][0] + b1r[0]);
                float v1 = tanhf_(cc[mt][nt][1] + b1r[1]);
                float v2 = tanhf_(cc[mt][nt][2] + b1r[2]);
                float v3 = tanhf_(cc[mt][nt][3] + b1r[3]);
                uint2 pk; pk.x = pk2(v0, v1); pk.y = pk2(v2, v3);
                *(uint2*)(sact + (srow + nt * 16 + l15) * 72 + mt * 16 + quad * 4) = pk;
            }
        }
        // ---- mv3: K=64 ----
        f32x4 ssf[4][2];
        #pragma unroll
        for (int mt = 0; mt < 4; mt++)
            #pragma unroll
            for (int nt = 0; nt < 2; nt++) ssf[mt][nt] = (f32x4){0.f, 0.f, 0.f, 0.f};
        #pragma unroll
        for (int kt = 0; kt < 2; kt++) {
            bf16x8 bf[2];
            #pragma unroll
            for (int nt = 0; nt < 2; nt++)
                bf[nt] = *(const bf16x8*)(sact + (srow + nt * 16 + l15) * 72 + kt * 32 + quad * 8);
            #pragma unroll
            for (int mt = 0; mt < 4; mt++) {
                bf16x8 af = *(const bf16x8*)(wA3 + (mt * 16 + l15) * 72 + kt * 32 + quad * 8);
                #pragma unroll
                for (int nt = 0; nt < 2; nt++)
                    ssf[mt][nt] = __builtin_amdgcn_mfma_f32_16x16x32_bf16(af, bf[nt], ssf[mt][nt], 0, 0, 0);
            }
        }
        // coupling in registers
        #pragma unroll
        for (int mt2 = 0; mt2 < 2; mt2++) {
            f32x4 b2s = *(const f32x4*)(parv + 384 + l * 64 +      mt2 * 16 + quad * 4);
            f32x4 b2h = *(const f32x4*)(parv + 384 + l * 64 + 32 + mt2 * 16 + quad * 4);
            f32x4 fa  = *(const f32x4*)(parv + 512 + l * 32 + mt2 * 16 + quad * 4);
            f32x4 fb  = *(const f32x4*)(parv + 576 + l * 32 + mt2 * 16 + quad * 4);
            const int xm = (l == 0) ? (mt2 + 2) : mt2;
            #pragma unroll
            for (int nt = 0; nt < 2; nt++) {
                #pragma unroll
                for (int r = 0; r < 4; r++) {
                    float sc  = ssf[mt2][nt][r] + b2s[r];
                    float sh  = ssf[mt2 + 2][nt][r] + b2h[r];
                    float tsc = tanhf_(tsv[nt] * fa[r]);
                    float tsh = tanhf_(tsv[nt] * fb[r]);
                    float xv  = xr[nt][xm][r];
                    xr[nt][xm][r] = xv * __expf(sc * tsc) + sh * tsh;
                }
                if (l == 0) {
                    uint2 pk;
                    pk.x = pk2(xr[nt][xm][0], xr[nt][xm][1]);
                    pk.y = pk2(xr[nt][xm][2], xr[nt][xm][3]);
                    *(uint2*)(sxk1 + (srow + nt * 16 + l15) * 40 + mt2 * 16 + quad * 4) = pk;
                }
            }
        }
    }
    // ---- intensity + per-block loss partial ----
    float contrib = 0.f;
    const float bi0 = bi[0];
    #pragma unroll
    for (int nt = 0; nt < 2; nt++) {
        float d0 = 0.f, d1 = 0.f;
        #pragma unroll
        for (int mt = 0; mt < 4; mt++) {
            f32x4 wi4 = *(const f32x4*)(parv + 640 + mt * 16 + quad * 4);
            d0 += xr[nt][mt][0] * wi4[0] + xr[nt][mt][2] * wi4[2];
            d1 += xr[nt][mt][1] * wi4[1] + xr[nt][mt][3] * wi4[3];
        }
        float d = d0 + d1;
        d += __shfl_xor(d, 16, 64);
        d += __shfl_xor(d, 32, 64);
        contrib += softplusf_(d + bi0) * sclf[nt];
    }
    if (quad != 0) contrib = 0.f;
    #pragma unroll
    for (int off = 1; off <= 8; off <<= 1) contrib += __shfl_xor(contrib, off, 64);
    if (l15 == 0 && quad == 0) pr[w] = contrib;
    __syncthreads();
    if (tid == 0) pp[blockIdx.x] = pr[0] + pr[1] + pr[2] + pr[3];
}

// ---------------------------------------------------------------------------
extern "C" __global__ __launch_bounds__(256)
void fin_kernel(const float* __restrict__ pp, float* __restrict__ out)
{
    __shared__ float r4[4];
    const int tid = threadIdx.x;
    float s = 0.f;
    for (int i = tid; i < (Bn * Tn) / 4; i += 256) s += pp[i];
    #pragma unroll
    for (int off = 32; off >= 1; off >>= 1) s += __shfl_xor(s, off, 64);
    if ((tid & 63) == 0) r4[tid >> 6] = s;
    __syncthreads();
    if (tid == 0) atomicAdd(out, r4[0] + r4[1] + r4[2] + r4[3]);
}

// ---------------------------------------------------------------------------
extern "C" void kernel_launch(void* const* d_in, const int* in_sizes, int n_in,
                              void* d_out, int out_size, void* d_ws, size_t ws_size,
                              hipStream_t stream)
{
    const float* times = (const float*)d_in[0];
    const int*   marks = (const int*)  d_in[1];
    const float* mask  = (const float*)d_in[2];
    const float* u     = (const float*)d_in[3];
    const float* emb   = (const float*)d_in[4];
    const float* fW0   = (const float*)d_in[5];
    const float* fb0   = (const float*)d_in[6];
    const float* fW1   = (const float*)d_in[7];
    const float* fb1   = (const float*)d_in[8];
    const float* fW2   = (const float*)d_in[9];
    const float* fb2   = (const float*)d_in[10];
    const float* ftw   = (const float*)d_in[11];
    const float* Wi    = (const float*)d_in[12];
    const float* bi    = (const float*)d_in[13];
    const float* W_ih  = (const float*)d_in[14];
    const float* W_hh  = (const float*)d_in[15];
    const float* b_ih  = (const float*)d_in[16];
    const float* b_hh  = (const float*)d_in[17];
    float* out = (float*)d_out;

    float* wsp     = (float*)d_ws;
    float* h_carry = wsp;                   // 2,097,152
    float* gc      = h_carry + 2097152;     // 65,536
    float* invd    = gc + 65536;            // 4
    float* seqw1T  = invd + 4;              // 8,704
    float* seqw2T  = seqw1T + 8704;         // 8,704
    float* whh260  = seqw2T + 8704;         // 16,640
    float* parv    = whh260 + 16640;        // 768
    unsigned short* parwb = (unsigned short*)(parv + 768);   // 23,552 ushorts
    float* pp      = (float*)(parwb + 23552);                // 8,192

    hipMemsetAsync(d_out, 0, sizeof(float), stream);

    prep_kernel<<<Bn + 8, 256, 0, stream>>>(marks, mask, emb, fW0, fW1, fW2,
                                            fb0, fb1, fb2, ftw, Wi, W_ih, W_hh,
                                            b_ih, b_hh, gc, invd, parv, parwb,
                                            seqw1T, seqw2T, whh260);
    seq_kernel<<<Bn, 64, 0, stream>>>(times, mask, fW0, fb0, fb1, fb2,
                                      ftw, Wi, bi, W_ih, gc, seqw1T, seqw2T,
                                      whh260, invd, h_carry, out);
    par_kernel<<<(Bn * Tn) / 4, 256, 0, stream>>>(
        times, mask, u, bi, invd, parv, parwb, h_carry, pp);
    fin_kernel<<<1, 256, 0, stream>>>(pp, out);
}